// Round 5
// baseline (885.641 us; speedup 1.0000x reference)
//
#include <hip/hip_runtime.h>
#include <hip/hip_bf16.h>

#define DD 128

typedef short bf16x8 __attribute__((ext_vector_type(8)));
typedef float f32x4 __attribute__((ext_vector_type(4)));

__device__ __forceinline__ float sigmoidf_(float v){ return 1.f/(1.f+__expf(-v)); }
__device__ __forceinline__ float tanhf_(float v){
  float e2 = __expf(2.f*v);
  return 1.f - 2.f/(e2 + 1.f);
}

__device__ __forceinline__ void bsplit(float v, unsigned short& hi, unsigned short& lo){
  __hip_bfloat16 h = __float2bfloat16(v);
  float hf = __bfloat162float(h);
  __hip_bfloat16 l = __float2bfloat16(v - hf);
  hi = *(unsigned short*)&h;
  lo = *(unsigned short*)&l;
}

// ---------- weight prep: decoder transpose (fp32) ----------
__global__ void k_prep(const float* __restrict__ W_dec, float* __restrict__ Wt_dec){
  int idx = blockIdx.x*256 + threadIdx.x;
  if (idx < 64*128){
    int j = idx / 128, k = idx % 128;
    int o = ((k>>2)*64 + j)*4 + (k&3);
    Wt_dec[o] = W_dec[idx];
  }
}

// ---------- weight prep: GRU weights -> bf16 hi/lo in B-fragment order ----------
// Tile nt in [0,24): fg = nt/3, gate = nt%3. Column j = gate*128 + fg*16 + (l&15).
// frag index fi = (((nt*4+ks)*64)+l)*8 + t ; k = ks*32 + ((l>>4)&3)*8 + t
__global__ void k_prep_frag(const float* __restrict__ W_ih, const float* __restrict__ W_hh,
                            unsigned short* __restrict__ Wih_hi, unsigned short* __restrict__ Wih_lo,
                            unsigned short* __restrict__ Whh_hi, unsigned short* __restrict__ Whh_lo){
  int idx = blockIdx.x*256 + threadIdx.x;
  const int TOT = 384*128;
  if (idx >= 2*TOT) return;
  const float* W = (idx < TOT) ? W_ih : W_hh;
  unsigned short* Dh = (idx < TOT) ? Wih_hi : Whh_hi;
  unsigned short* Dl = (idx < TOT) ? Wih_lo : Whh_lo;
  int fi = (idx < TOT) ? idx : idx - TOT;
  int t = fi & 7;
  int l = (fi >> 3) & 63;
  int ks = (fi >> 9) & 3;
  int nt = fi >> 11;
  int fg = nt / 3, gate = nt % 3;
  int j = gate*128 + fg*16 + (l & 15);
  int k = ks*32 + ((l >> 4) & 3)*8 + t;
  unsigned short hi, lo;
  bsplit(W[j*128 + k], hi, lo);
  Dh[fi] = hi; Dl[fi] = lo;
}

// ---------- encoder ----------
__global__ void __launch_bounds__(128) k_enc(const float* __restrict__ x,
                        const float* __restrict__ W_enc,
                        float* __restrict__ h0, float* __restrict__ stats, int N){
  const int f = threadIdx.x;
  const float w0 = W_enc[f*3], w1 = W_enc[f*3+1], w2 = W_enc[f*3+2];
  const int chunk = (N + gridDim.x - 1) / gridDim.x;
  const int n0 = blockIdx.x * chunk;
  const int n1 = (n0 + chunk < N) ? (n0 + chunk) : N;
  float s = 0.f, q = 0.f;
  for (int n = n0; n < n1; n++){
    float x0 = x[n*3], x1 = x[n*3+1], x2 = x[n*3+2];
    float h = x0*w0 + x1*w1 + x2*w2;
    h0[(size_t)n*DD + f] = h;
    s += h; q += h*h;
  }
  atomicAdd(&stats[f], s);
  atomicAdd(&stats[DD+f], q);
}

__global__ void k_enc_apply(const float* __restrict__ h0, const float* __restrict__ gamma,
                            const float* __restrict__ beta, const float* __restrict__ stats,
                            float* __restrict__ prev_h, float* __restrict__ h_sum,
                            unsigned short* __restrict__ ph_hi, unsigned short* __restrict__ ph_lo, int N){
  int idx = blockIdx.x*256 + threadIdx.x;
  if (idx >= N*DD) return;
  int f = idx & (DD-1);
  float invN = 1.f / (float)N;
  float mu = stats[f] * invN;
  float var = stats[DD+f] * invN - mu*mu;
  float v = (h0[idx] - mu) * rsqrtf(var + 1e-5f) * gamma[f] + beta[f];
  v = fmaxf(v, 0.f);
  prev_h[idx] = v;
  h_sum[idx]  = v;
  unsigned short hi, lo; bsplit(v, hi, lo);
  ph_hi[idx] = hi; ph_lo[idx] = lo;
}

// ---------- CSR build ----------
__global__ void k_hist(const int* __restrict__ dst, int* __restrict__ counts, int E){
  int e = blockIdx.x*256 + threadIdx.x;
  if (e < E) atomicAdd(&counts[dst[e]], 1);
}

__global__ void __launch_bounds__(256) k_scan_part(const int* __restrict__ counts,
                                                   int* __restrict__ partials, int N){
  int i = blockIdx.x*256 + threadIdx.x;
  int v = (i < N) ? counts[i] : 0;
  #pragma unroll
  for (int off = 32; off > 0; off >>= 1) v += __shfl_down(v, off, 64);
  __shared__ int red[4];
  if ((threadIdx.x & 63) == 0) red[threadIdx.x >> 6] = v;
  __syncthreads();
  if (threadIdx.x == 0) partials[blockIdx.x] = red[0]+red[1]+red[2]+red[3];
}

__global__ void __launch_bounds__(256) k_scan_mid(int* __restrict__ partials, int P,
                                                  int* __restrict__ offsets, int N){
  __shared__ int lds[4];
  __shared__ int carry_s;
  const int lane = threadIdx.x & 63, wid = threadIdx.x >> 6;
  if (threadIdx.x == 0) carry_s = 0;
  __syncthreads();
  for (int base = 0; base < P; base += 256){
    int i = base + threadIdx.x;
    int v = (i < P) ? partials[i] : 0;
    int orig = v;
    #pragma unroll
    for (int off = 1; off < 64; off <<= 1){
      int u = __shfl_up(v, off, 64);
      if (lane >= off) v += u;
    }
    if (lane == 63) lds[wid] = v;
    __syncthreads();
    if (threadIdx.x == 0){
      int s = carry_s;
      for (int k = 0; k < 4; k++){ int t = lds[k]; lds[k] = s; s += t; }
      carry_s = s;
    }
    __syncthreads();
    int excl = v - orig + lds[wid];
    if (i < P) partials[i] = excl;
    __syncthreads();
  }
  if (threadIdx.x == 0) offsets[N] = carry_s;
}

__global__ void __launch_bounds__(256) k_scan_expand(const int* __restrict__ counts,
        const int* __restrict__ partials, int* __restrict__ offsets,
        int* __restrict__ cursors, int N){
  int i = blockIdx.x*256 + threadIdx.x;
  int v = (i < N) ? counts[i] : 0;
  int orig = v;
  const int lane = threadIdx.x & 63, wid = threadIdx.x >> 6;
  #pragma unroll
  for (int off = 1; off < 64; off <<= 1){
    int u = __shfl_up(v, off, 64);
    if (lane >= off) v += u;
  }
  __shared__ int lds[4];
  if (lane == 63) lds[wid] = v;
  __syncthreads();
  int wbase = 0;
  for (int k = 0; k < wid; k++) wbase += lds[k];
  int excl = partials[blockIdx.x] + wbase + v - orig;
  if (i < N){ offsets[i] = excl; cursors[i] = excl; }
}

__global__ void k_fill(const int* __restrict__ src, const int* __restrict__ dst,
                       const float* __restrict__ norm, int* __restrict__ cursors,
                       int* __restrict__ csr_src, float* __restrict__ csr_norm, int E){
  int e = blockIdx.x*256 + threadIdx.x;
  if (e >= E) return;
  int p = atomicAdd(&cursors[dst[e]], 1);
  csr_src[p] = src[e];
  csr_norm[p] = norm[e];
}

// ---------- fused layer: gather -> LDS -> MFMA -> gates ----------
// 256 threads = 4 waves, 32 nodes/block. ONE barrier (after gather); ph is
// double-buffered so the epilogue never races other waves' A-frag reads.
// Phase1: 8 half-waves x 4 passes gather; h_sum RMW fused; 8-deep edge unroll.
// Phase2+3: wave w handles feature groups fg = 2w, 2w+1 sequentially:
//   K-loop (A from LDS + ph_cur global, B streamed from L2) then register gates.
// LDS swizzle: 16B chunk c of row m stored at chunk c^(m&7).
__global__ void __launch_bounds__(256, 4) k_layer(
        const float* __restrict__ prev_cur, float* __restrict__ prev_nxt,
        const unsigned short* __restrict__ phc_hi, const unsigned short* __restrict__ phc_lo,
        unsigned short* __restrict__ phn_hi, unsigned short* __restrict__ phn_lo,
        float* __restrict__ h_sum,
        const int* __restrict__ offsets, const int* __restrict__ csr_src,
        const float* __restrict__ csr_norm,
        const unsigned short* __restrict__ Wih_hi, const unsigned short* __restrict__ Wih_lo,
        const unsigned short* __restrict__ Whh_hi, const unsigned short* __restrict__ Whh_lo,
        const float* __restrict__ b_ih, const float* __restrict__ b_hh, int N){
  __shared__ unsigned short s_ah[32*DD];
  __shared__ unsigned short s_al[32*DD];
  const int tid = threadIdx.x;
  const int n0 = blockIdx.x * 32;

  // ---- phase 1: gather ----
  {
    const int hw = tid >> 5;
    const int q  = tid & 31;
    #pragma unroll
    for (int pass = 0; pass < 4; pass++){
      const int m = hw + pass*8;
      const int n = n0 + m;
      float ax=0.f, ay=0.f, az=0.f, aw=0.f;
      if (n < N){
        const int s0 = offsets[n], s1 = offsets[n+1];
        int i = s0;
        for (; i + 8 <= s1; i += 8){
          int   sE[8]; float wE[8];
          #pragma unroll
          for (int u = 0; u < 8; u++){ sE[u] = csr_src[i+u]; wE[u] = csr_norm[i+u]; }
          float4 R[8];
          #pragma unroll
          for (int u = 0; u < 8; u++) R[u] = *(const float4*)(prev_cur + (size_t)sE[u]*DD + q*4);
          #pragma unroll
          for (int u = 0; u < 8; u++){
            ax = fmaf(wE[u],R[u].x,ax); ay = fmaf(wE[u],R[u].y,ay);
            az = fmaf(wE[u],R[u].z,az); aw = fmaf(wE[u],R[u].w,aw);
          }
        }
        if (i + 4 <= s1){
          int   sE[4]; float wE[4];
          #pragma unroll
          for (int u = 0; u < 4; u++){ sE[u] = csr_src[i+u]; wE[u] = csr_norm[i+u]; }
          float4 R[4];
          #pragma unroll
          for (int u = 0; u < 4; u++) R[u] = *(const float4*)(prev_cur + (size_t)sE[u]*DD + q*4);
          #pragma unroll
          for (int u = 0; u < 4; u++){
            ax = fmaf(wE[u],R[u].x,ax); ay = fmaf(wE[u],R[u].y,ay);
            az = fmaf(wE[u],R[u].z,az); aw = fmaf(wE[u],R[u].w,aw);
          }
          i += 4;
        }
        for (; i < s1; i++){
          int s = csr_src[i];
          float w = csr_norm[i];
          float4 A = *(const float4*)(prev_cur + (size_t)s*DD + q*4);
          ax = fmaf(w,A.x,ax); ay = fmaf(w,A.y,ay); az = fmaf(w,A.z,az); aw = fmaf(w,A.w,aw);
        }
        size_t o = (size_t)n*DD + q*4;
        float4 hs = *(const float4*)(h_sum + o);
        hs.x += ax; hs.y += ay; hs.z += az; hs.w += aw;
        *(float4*)(h_sum + o) = hs;
      }
      ushort4 vhi, vlo;
      bsplit(ax, vhi.x, vlo.x); bsplit(ay, vhi.y, vlo.y);
      bsplit(az, vhi.z, vlo.z); bsplit(aw, vhi.w, vlo.w);
      int cc = (q >> 1) ^ (m & 7);
      int off = m*DD + cc*8 + (q & 1)*4;
      *(ushort4*)(s_ah + off) = vhi;
      *(ushort4*)(s_al + off) = vlo;
    }
  }
  __syncthreads();   // the only barrier: LDS A-frags ready

  // ---- phase 2+3 per feature group ----
  const int w = tid >> 6, l = tid & 63, ar = l & 15, aq = l >> 4;
  int r0 = n0 + ar;      if (r0 >= N) r0 = N-1;
  int r1 = n0 + 16 + ar; if (r1 >= N) r1 = N-1;
  const size_t p0 = (size_t)r0*DD + aq*8;
  const size_t p1 = (size_t)r1*DD + aq*8;
  const int sw = ar & 7;

  for (int g = 0; g < 2; g++){
    const int fg = w*2 + g;
    f32x4 acc_i[2][3], acc_h[2][3];
    #pragma unroll
    for (int ta = 0; ta < 2; ta++)
      #pragma unroll
      for (int t = 0; t < 3; t++){
        acc_i[ta][t] = (f32x4){0.f,0.f,0.f,0.f};
        acc_h[ta][t] = (f32x4){0.f,0.f,0.f,0.f};
      }

    #pragma unroll
    for (int ks = 0; ks < 4; ks++){
      const int c = (ks*4 + aq) ^ sw;
      bf16x8 ih0 = *(const bf16x8*)(s_ah + ar*DD       + c*8);
      bf16x8 ih1 = *(const bf16x8*)(s_ah + (16+ar)*DD  + c*8);
      bf16x8 il0 = *(const bf16x8*)(s_al + ar*DD       + c*8);
      bf16x8 il1 = *(const bf16x8*)(s_al + (16+ar)*DD  + c*8);
      bf16x8 hh0 = *(const bf16x8*)(phc_hi + p0 + ks*32);
      bf16x8 hh1 = *(const bf16x8*)(phc_hi + p1 + ks*32);
      bf16x8 hl0 = *(const bf16x8*)(phc_lo + p0 + ks*32);
      bf16x8 hl1 = *(const bf16x8*)(phc_lo + p1 + ks*32);
      #pragma unroll
      for (int t = 0; t < 3; t++){
        size_t bo = ((size_t)((fg*3 + t)*4 + ks)*64 + l)*8;
        bf16x8 bih = *(const bf16x8*)(Wih_hi + bo);
        bf16x8 bil = *(const bf16x8*)(Wih_lo + bo);
        bf16x8 bhh = *(const bf16x8*)(Whh_hi + bo);
        bf16x8 bhl = *(const bf16x8*)(Whh_lo + bo);
        acc_i[0][t] = __builtin_amdgcn_mfma_f32_16x16x32_bf16(ih0, bih, acc_i[0][t], 0, 0, 0);
        acc_i[0][t] = __builtin_amdgcn_mfma_f32_16x16x32_bf16(ih0, bil, acc_i[0][t], 0, 0, 0);
        acc_i[0][t] = __builtin_amdgcn_mfma_f32_16x16x32_bf16(il0, bih, acc_i[0][t], 0, 0, 0);
        acc_i[1][t] = __builtin_amdgcn_mfma_f32_16x16x32_bf16(ih1, bih, acc_i[1][t], 0, 0, 0);
        acc_i[1][t] = __builtin_amdgcn_mfma_f32_16x16x32_bf16(ih1, bil, acc_i[1][t], 0, 0, 0);
        acc_i[1][t] = __builtin_amdgcn_mfma_f32_16x16x32_bf16(il1, bih, acc_i[1][t], 0, 0, 0);
        acc_h[0][t] = __builtin_amdgcn_mfma_f32_16x16x32_bf16(hh0, bhh, acc_h[0][t], 0, 0, 0);
        acc_h[0][t] = __builtin_amdgcn_mfma_f32_16x16x32_bf16(hh0, bhl, acc_h[0][t], 0, 0, 0);
        acc_h[0][t] = __builtin_amdgcn_mfma_f32_16x16x32_bf16(hl0, bhh, acc_h[0][t], 0, 0, 0);
        acc_h[1][t] = __builtin_amdgcn_mfma_f32_16x16x32_bf16(hh1, bhh, acc_h[1][t], 0, 0, 0);
        acc_h[1][t] = __builtin_amdgcn_mfma_f32_16x16x32_bf16(hh1, bhl, acc_h[1][t], 0, 0, 0);
        acc_h[1][t] = __builtin_amdgcn_mfma_f32_16x16x32_bf16(hl1, bhh, acc_h[1][t], 0, 0, 0);
      }
    }

    const int f = fg*16 + ar;
    const float bir = b_ih[f], biz = b_ih[128+f], bin_ = b_ih[256+f];
    const float bhr = b_hh[f], bhz = b_hh[128+f], bhn = b_hh[256+f];
    #pragma unroll
    for (int ta = 0; ta < 2; ta++){
      #pragma unroll
      for (int r = 0; r < 4; r++){
        int n = n0 + ta*16 + aq*4 + r;
        if (n < N){
          float sir = acc_i[ta][0][r] + bir, shr = acc_h[ta][0][r] + bhr;
          float siz = acc_i[ta][1][r] + biz, shz = acc_h[ta][1][r] + bhz;
          float sin_ = acc_i[ta][2][r] + bin_, shn = acc_h[ta][2][r] + bhn;
          float rr = sigmoidf_(sir + shr);
          float zz = sigmoidf_(siz + shz);
          float nn = tanhf_(sin_ + rr*shn);
          size_t o = (size_t)n*DD + f;
          float hp = prev_cur[o];
          float h = (1.f - zz)*nn + zz*hp;
          prev_nxt[o] = h;
          unsigned short hi, lo; bsplit(h, hi, lo);
          phn_hi[o] = hi; phn_lo[o] = lo;
        }
      }
    }
  }
}

// ---------- decoder stage 1: 8 split stats copies to cap atomic contention ----------
__global__ void __launch_bounds__(256) k_dec1(const float* __restrict__ h_sum,
        const float* __restrict__ Wt_dec, float* __restrict__ y1,
        float* __restrict__ stats_d, int N){
  const int j = threadIdx.x & 63;
  const int slot = threadIdx.x >> 6;
  float s = 0.f, q = 0.f;
  for (int n = blockIdx.x*4 + slot; n < N; n += gridDim.x*4){
    float acc = 0.f;
    for (int k = 0; k < DD; k += 4){
      float4 zv = *(const float4*)(h_sum + (size_t)n*DD + k);
      float4 wv = *(const float4*)(Wt_dec + ((size_t)(k>>2)*64 + j)*4);
      acc += zv.x*wv.x + zv.y*wv.y + zv.z*wv.z + zv.w*wv.w;
    }
    acc *= (1.f/6.f);
    y1[(size_t)n*64 + j] = acc;
    s += acc; q += acc*acc;
  }
  __shared__ float red[2][4][64];
  red[0][slot][j] = s; red[1][slot][j] = q;
  __syncthreads();
  if (slot == 0){
    s = red[0][0][j] + red[0][1][j] + red[0][2][j] + red[0][3][j];
    q = red[1][0][j] + red[1][1][j] + red[1][2][j] + red[1][3][j];
    float* st = stats_d + (size_t)(blockIdx.x & 7)*128;
    atomicAdd(&st[j], s);
    atomicAdd(&st[64+j], q);
  }
}

// ---------- decoder stage 2: sum stats copies, bn + relu + dot ----------
__global__ void __launch_bounds__(256) k_dec2(const float* __restrict__ y1,
        const float* __restrict__ gamma, const float* __restrict__ beta,
        const float* __restrict__ W_dec2, const float* __restrict__ stats_d,
        float* __restrict__ out, int N){
  const int j = threadIdx.x & 63;
  const int g = threadIdx.x >> 6;
  const int n = blockIdx.x*4 + g;
  if (n >= N) return;
  float ssum = 0.f, qsum = 0.f;
  #pragma unroll
  for (int c = 0; c < 8; c++){
    ssum += stats_d[c*128 + j];
    qsum += stats_d[c*128 + 64 + j];
  }
  float invN = 1.f / (float)N;
  float mu = ssum * invN;
  float var = qsum * invN - mu*mu;
  float v = (y1[(size_t)n*64 + j] - mu) * rsqrtf(var + 1e-5f) * gamma[j] + beta[j];
  v = fmaxf(v, 0.f) * W_dec2[j];
  for (int off = 32; off > 0; off >>= 1) v += __shfl_down(v, off, 64);
  if (j == 0) out[n] = v;
}

extern "C" void kernel_launch(void* const* d_in, const int* in_sizes, int n_in,
                              void* d_out, int out_size, void* d_ws, size_t ws_size,
                              hipStream_t stream) {
  const int N = in_sizes[0] / 3;
  const int E = in_sizes[1] / 2;
  const int P = (N + 255) / 256;

  const float* x     = (const float*)d_in[0];
  const int*   ei    = (const int*)d_in[1];
  const int*   src   = ei;
  const int*   dst   = ei + E;
  const float* norm  = (const float*)d_in[2];
  const float* W_enc = (const float*)d_in[3];
  const float* g_e   = (const float*)d_in[4];
  const float* b_e   = (const float*)d_in[5];
  const float* W_ih  = (const float*)d_in[6];
  const float* W_hh  = (const float*)d_in[7];
  const float* b_ih  = (const float*)d_in[8];
  const float* b_hh  = (const float*)d_in[9];
  const float* W_dec = (const float*)d_in[10];
  const float* g_d   = (const float*)d_in[11];
  const float* b_d   = (const float*)d_in[12];
  const float* W_dec2= (const float*)d_in[13];
  float* out = (float*)d_out;

  float* ws = (float*)d_ws;
  const size_t NF = (size_t)N * DD;
  float* bufA   = ws;                        // NF fp32
  float* bufB   = bufA + NF;                 // NF fp32 (h0 before loop)
  float* h_sum  = bufB + NF;                 // NF
  float* stats  = h_sum + NF;                // 256 enc + 1024 dec
  float* Wt_dec = stats + 1280;              // 64*128
  unsigned short* Wih_hi = (unsigned short*)(Wt_dec + 64*128);
  unsigned short* Wih_lo = Wih_hi + 384*128;
  unsigned short* Whh_hi = Wih_lo + 384*128;
  unsigned short* Whh_lo = Whh_hi + 384*128;
  unsigned short* ph_hiA = Whh_lo + 384*128; // NF ushorts each
  unsigned short* ph_loA = ph_hiA + NF;
  unsigned short* ph_hiB = ph_loA + NF;
  unsigned short* ph_loB = ph_hiB + NF;
  int*   counts  = (int*)(ph_loB + NF);      // N
  int*   offsets = counts + N;               // N+1
  int*   cursors = offsets + N + 1;          // N
  int*   partials= cursors + N;              // P
  int*   csr_src = partials + P;             // E
  float* csr_norm = (float*)(csr_src + E);   // E
  float* h0 = bufB;                          // consumed before layer 0 writes bufB
  float* y1 = bufA;                          // decoder scratch (bufA dead after loop: 5 layers end in bufB)

  hipMemsetAsync(stats, 0, 1280*sizeof(float), stream);
  hipMemsetAsync(counts, 0, (size_t)N*sizeof(int), stream);

  k_prep<<<(64*128 + 255)/256, 256, 0, stream>>>(W_dec, Wt_dec);
  k_prep_frag<<<(2*384*128 + 255)/256, 256, 0, stream>>>(W_ih, W_hh, Wih_hi, Wih_lo, Whh_hi, Whh_lo);
  k_enc<<<256, 128, 0, stream>>>(x, W_enc, h0, stats, N);
  k_enc_apply<<<(N*DD + 255)/256, 256, 0, stream>>>(h0, g_e, b_e, stats, bufA, h_sum, ph_hiA, ph_loA, N);

  k_hist<<<(E + 255)/256, 256, 0, stream>>>(dst, counts, E);
  k_scan_part<<<P, 256, 0, stream>>>(counts, partials, N);
  k_scan_mid<<<1, 256, 0, stream>>>(partials, P, offsets, N);
  k_scan_expand<<<P, 256, 0, stream>>>(counts, partials, offsets, cursors, N);
  k_fill<<<(E + 255)/256, 256, 0, stream>>>(src, dst, norm, cursors, csr_src, csr_norm, E);

  float* cur = bufA;            float* nxt = bufB;
  unsigned short* phh_c = ph_hiA; unsigned short* phl_c = ph_loA;
  unsigned short* phh_n = ph_hiB; unsigned short* phl_n = ph_loB;
  for (int l = 0; l < 5; l++){
    k_layer<<<(N + 31)/32, 256, 0, stream>>>(cur, nxt, phh_c, phl_c, phh_n, phl_n, h_sum,
                                             offsets, csr_src, csr_norm,
                                             Wih_hi, Wih_lo, Whh_hi, Whh_lo, b_ih, b_hh, N);
    { float* t = cur; cur = nxt; nxt = t; }
    { unsigned short* t = phh_c; phh_c = phh_n; phh_n = t; }
    { unsigned short* t = phl_c; phl_c = phl_n; phl_n = t; }
  }

  k_dec1<<<1024, 256, 0, stream>>>(h_sum, Wt_dec, y1, stats + 256, N);
  k_dec2<<<(N + 3)/4, 256, 0, stream>>>(y1, g_d, b_d, W_dec2, stats + 256, out, N);
}

// Round 6
// 736.275 us; speedup vs baseline: 1.2029x; 1.2029x over previous
//
#include <hip/hip_runtime.h>
#include <hip/hip_bf16.h>

#define DD 128

typedef short bf16x8 __attribute__((ext_vector_type(8)));
typedef unsigned short u16x8 __attribute__((ext_vector_type(8)));
typedef float f32x4 __attribute__((ext_vector_type(4)));

__device__ __forceinline__ float sigmoidf_(float v){ return 1.f/(1.f+__expf(-v)); }
__device__ __forceinline__ float tanhf_(float v){
  float e2 = __expf(2.f*v);
  return 1.f - 2.f/(e2 + 1.f);
}
__device__ __forceinline__ float b2f(unsigned short u){
  unsigned int x = ((unsigned int)u) << 16;
  union { unsigned int i; float f; } c; c.i = x; return c.f;
}
__device__ __forceinline__ void bsplit(float v, unsigned short& hi, unsigned short& lo){
  __hip_bfloat16 h = __float2bfloat16(v);
  float hf = __bfloat162float(h);
  __hip_bfloat16 l = __float2bfloat16(v - hf);
  hi = *(unsigned short*)&h;
  lo = *(unsigned short*)&l;
}

// ---------- weight prep: decoder transpose (fp32) ----------
__global__ void k_prep(const float* __restrict__ W_dec, float* __restrict__ Wt_dec){
  int idx = blockIdx.x*256 + threadIdx.x;
  if (idx < 64*128){
    int j = idx / 128, k = idx % 128;
    int o = ((k>>2)*64 + j)*4 + (k&3);
    Wt_dec[o] = W_dec[idx];
  }
}

// ---------- weight prep: GRU weights -> bf16 hi/lo in B-fragment order ----------
// Tile nt in [0,24): fg = nt/3, gate = nt%3. Column j = gate*128 + fg*16 + (l&15).
// frag index fi = (((nt*4+ks)*64)+l)*8 + t ; k = ks*32 + ((l>>4)&3)*8 + t
__global__ void k_prep_frag(const float* __restrict__ W_ih, const float* __restrict__ W_hh,
                            unsigned short* __restrict__ Wih_hi, unsigned short* __restrict__ Wih_lo,
                            unsigned short* __restrict__ Whh_hi, unsigned short* __restrict__ Whh_lo){
  int idx = blockIdx.x*256 + threadIdx.x;
  const int TOT = 384*128;
  if (idx >= 2*TOT) return;
  const float* W = (idx < TOT) ? W_ih : W_hh;
  unsigned short* Dh = (idx < TOT) ? Wih_hi : Whh_hi;
  unsigned short* Dl = (idx < TOT) ? Wih_lo : Whh_lo;
  int fi = (idx < TOT) ? idx : idx - TOT;
  int t = fi & 7;
  int l = (fi >> 3) & 63;
  int ks = (fi >> 9) & 3;
  int nt = fi >> 11;
  int fg = nt / 3, gate = nt % 3;
  int j = gate*128 + fg*16 + (l & 15);
  int k = ks*32 + ((l >> 4) & 3)*8 + t;
  unsigned short hi, lo;
  bsplit(W[j*128 + k], hi, lo);
  Dh[fi] = hi; Dl[fi] = lo;
}

// ---------- encoder ----------
__global__ void __launch_bounds__(128) k_enc(const float* __restrict__ x,
                        const float* __restrict__ W_enc,
                        float* __restrict__ h0, float* __restrict__ stats, int N){
  const int f = threadIdx.x;
  const float w0 = W_enc[f*3], w1 = W_enc[f*3+1], w2 = W_enc[f*3+2];
  const int chunk = (N + gridDim.x - 1) / gridDim.x;
  const int n0 = blockIdx.x * chunk;
  const int n1 = (n0 + chunk < N) ? (n0 + chunk) : N;
  float s = 0.f, q = 0.f;
  for (int n = n0; n < n1; n++){
    float x0 = x[n*3], x1 = x[n*3+1], x2 = x[n*3+2];
    float h = x0*w0 + x1*w1 + x2*w2;
    h0[(size_t)n*DD + f] = h;
    s += h; q += h*h;
  }
  atomicAdd(&stats[f], s);
  atomicAdd(&stats[DD+f], q);
}

__global__ void k_enc_apply(const float* __restrict__ h0, const float* __restrict__ gamma,
                            const float* __restrict__ beta, const float* __restrict__ stats,
                            float* __restrict__ h_sum,
                            unsigned short* __restrict__ ph_hi, unsigned short* __restrict__ ph_lo, int N){
  int idx = blockIdx.x*256 + threadIdx.x;
  if (idx >= N*DD) return;
  int f = idx & (DD-1);
  float invN = 1.f / (float)N;
  float mu = stats[f] * invN;
  float var = stats[DD+f] * invN - mu*mu;
  float v = (h0[idx] - mu) * rsqrtf(var + 1e-5f) * gamma[f] + beta[f];
  v = fmaxf(v, 0.f);
  h_sum[idx] = v;
  unsigned short hi, lo; bsplit(v, hi, lo);
  ph_hi[idx] = hi; ph_lo[idx] = lo;
}

// ---------- CSR build ----------
__global__ void k_hist(const int* __restrict__ dst, int* __restrict__ counts, int E){
  int e = blockIdx.x*256 + threadIdx.x;
  if (e < E) atomicAdd(&counts[dst[e]], 1);
}

__global__ void __launch_bounds__(256) k_scan_part(const int* __restrict__ counts,
                                                   int* __restrict__ partials, int N){
  int i = blockIdx.x*256 + threadIdx.x;
  int v = (i < N) ? counts[i] : 0;
  #pragma unroll
  for (int off = 32; off > 0; off >>= 1) v += __shfl_down(v, off, 64);
  __shared__ int red[4];
  if ((threadIdx.x & 63) == 0) red[threadIdx.x >> 6] = v;
  __syncthreads();
  if (threadIdx.x == 0) partials[blockIdx.x] = red[0]+red[1]+red[2]+red[3];
}

__global__ void __launch_bounds__(256) k_scan_mid(int* __restrict__ partials, int P,
                                                  int* __restrict__ offsets, int N){
  __shared__ int lds[4];
  __shared__ int carry_s;
  const int lane = threadIdx.x & 63, wid = threadIdx.x >> 6;
  if (threadIdx.x == 0) carry_s = 0;
  __syncthreads();
  for (int base = 0; base < P; base += 256){
    int i = base + threadIdx.x;
    int v = (i < P) ? partials[i] : 0;
    int orig = v;
    #pragma unroll
    for (int off = 1; off < 64; off <<= 1){
      int u = __shfl_up(v, off, 64);
      if (lane >= off) v += u;
    }
    if (lane == 63) lds[wid] = v;
    __syncthreads();
    if (threadIdx.x == 0){
      int s = carry_s;
      for (int k = 0; k < 4; k++){ int t = lds[k]; lds[k] = s; s += t; }
      carry_s = s;
    }
    __syncthreads();
    int excl = v - orig + lds[wid];
    if (i < P) partials[i] = excl;
    __syncthreads();
  }
  if (threadIdx.x == 0) offsets[N] = carry_s;
}

__global__ void __launch_bounds__(256) k_scan_expand(const int* __restrict__ counts,
        const int* __restrict__ partials, int* __restrict__ offsets,
        int* __restrict__ cursors, int N){
  int i = blockIdx.x*256 + threadIdx.x;
  int v = (i < N) ? counts[i] : 0;
  int orig = v;
  const int lane = threadIdx.x & 63, wid = threadIdx.x >> 6;
  #pragma unroll
  for (int off = 1; off < 64; off <<= 1){
    int u = __shfl_up(v, off, 64);
    if (lane >= off) v += u;
  }
  __shared__ int lds[4];
  if (lane == 63) lds[wid] = v;
  __syncthreads();
  int wbase = 0;
  for (int k = 0; k < wid; k++) wbase += lds[k];
  int excl = partials[blockIdx.x] + wbase + v - orig;
  if (i < N){ offsets[i] = excl; cursors[i] = excl; }
}

__global__ void k_fill(const int* __restrict__ src, const int* __restrict__ dst,
                       const float* __restrict__ norm, int* __restrict__ cursors,
                       int* __restrict__ csr_src, float* __restrict__ csr_norm, int E){
  int e = blockIdx.x*256 + threadIdx.x;
  if (e >= E) return;
  int p = atomicAdd(&cursors[dst[e]], 1);
  csr_src[p] = src[e];
  csr_norm[p] = norm[e];
}

// ---------- fused layer: bf16 gather -> LDS -> MFMA -> gates ----------
// h lives ONLY as bf16 hi/lo pair (double-buffered). Gather reads hi-only
// (bf16 message precision, ~2e-3 rel); GRU h-path keeps hi+lo accuracy.
// 256 threads. Phase1: 16 node-slots x 16 lanes x 2 passes; lane = 8-feature
// octet (16B bf16 load per edge row). h_sum RMW fused.
// Phase2+3: wave w handles fg = 2w, 2w+1; A(agg) from LDS, A(ph) hi/lo global.
// LDS swizzle: 16B chunk c of row m at c^(m&7).
__global__ void __launch_bounds__(256, 4) k_layer(
        const unsigned short* __restrict__ phc_hi, const unsigned short* __restrict__ phc_lo,
        unsigned short* __restrict__ phn_hi, unsigned short* __restrict__ phn_lo,
        float* __restrict__ h_sum,
        const int* __restrict__ offsets, const int* __restrict__ csr_src,
        const float* __restrict__ csr_norm,
        const unsigned short* __restrict__ Wih_hi, const unsigned short* __restrict__ Wih_lo,
        const unsigned short* __restrict__ Whh_hi, const unsigned short* __restrict__ Whh_lo,
        const float* __restrict__ b_ih, const float* __restrict__ b_hh, int N){
  __shared__ unsigned short s_ah[32*DD];
  __shared__ unsigned short s_al[32*DD];
  const int tid = threadIdx.x;
  const int n0 = blockIdx.x * 32;

  // ---- phase 1: gather (bf16 rows) ----
  {
    const int slot = tid >> 4;   // node slot 0..15
    const int q    = tid & 15;   // feature octet
    #pragma unroll
    for (int pass = 0; pass < 2; pass++){
      const int m = slot + pass*16;
      const int n = n0 + m;
      float acc[8];
      #pragma unroll
      for (int t = 0; t < 8; t++) acc[t] = 0.f;
      if (n < N){
        const int s0 = offsets[n], s1 = offsets[n+1];
        int i = s0;
        for (; i + 8 <= s1; i += 8){
          int sE[8]; float wE[8]; bf16x8 R[8];
          #pragma unroll
          for (int u = 0; u < 8; u++){ sE[u] = csr_src[i+u]; wE[u] = csr_norm[i+u]; }
          #pragma unroll
          for (int u = 0; u < 8; u++) R[u] = *(const bf16x8*)(phc_hi + (size_t)sE[u]*DD + q*8);
          #pragma unroll
          for (int u = 0; u < 8; u++)
            #pragma unroll
            for (int t = 0; t < 8; t++)
              acc[t] = fmaf(wE[u], b2f((unsigned short)R[u][t]), acc[t]);
        }
        if (i + 4 <= s1){
          int sE[4]; float wE[4]; bf16x8 R[4];
          #pragma unroll
          for (int u = 0; u < 4; u++){ sE[u] = csr_src[i+u]; wE[u] = csr_norm[i+u]; }
          #pragma unroll
          for (int u = 0; u < 4; u++) R[u] = *(const bf16x8*)(phc_hi + (size_t)sE[u]*DD + q*8);
          #pragma unroll
          for (int u = 0; u < 4; u++)
            #pragma unroll
            for (int t = 0; t < 8; t++)
              acc[t] = fmaf(wE[u], b2f((unsigned short)R[u][t]), acc[t]);
          i += 4;
        }
        for (; i < s1; i++){
          int s = csr_src[i];
          float w = csr_norm[i];
          bf16x8 R = *(const bf16x8*)(phc_hi + (size_t)s*DD + q*8);
          #pragma unroll
          for (int t = 0; t < 8; t++)
            acc[t] = fmaf(w, b2f((unsigned short)R[t]), acc[t]);
        }
        // h_sum RMW (coalesced: 16 lanes x 32B = full row)
        size_t o = (size_t)n*DD + q*8;
        float4 h1 = *(const float4*)(h_sum + o);
        float4 h2 = *(const float4*)(h_sum + o + 4);
        h1.x += acc[0]; h1.y += acc[1]; h1.z += acc[2]; h1.w += acc[3];
        h2.x += acc[4]; h2.y += acc[5]; h2.z += acc[6]; h2.w += acc[7];
        *(float4*)(h_sum + o) = h1;
        *(float4*)(h_sum + o + 4) = h2;
      }
      u16x8 vhi, vlo;
      #pragma unroll
      for (int t = 0; t < 8; t++){
        unsigned short hi, lo; bsplit(acc[t], hi, lo);
        vhi[t] = hi; vlo[t] = lo;
      }
      const int cc = q ^ (m & 7);
      const int off = m*DD + cc*8;
      *(u16x8*)(s_ah + off) = vhi;
      *(u16x8*)(s_al + off) = vlo;
    }
  }
  __syncthreads();   // the only barrier: LDS A-frags ready

  // ---- phase 2+3 per feature group ----
  const int w = tid >> 6, l = tid & 63, ar = l & 15, aq = l >> 4;
  int r0 = n0 + ar;      if (r0 >= N) r0 = N-1;
  int r1 = n0 + 16 + ar; if (r1 >= N) r1 = N-1;
  const size_t p0 = (size_t)r0*DD + aq*8;
  const size_t p1 = (size_t)r1*DD + aq*8;
  const int sw = ar & 7;

  for (int g = 0; g < 2; g++){
    const int fg = w*2 + g;
    f32x4 acc_i[2][3], acc_h[2][3];
    #pragma unroll
    for (int ta = 0; ta < 2; ta++)
      #pragma unroll
      for (int t = 0; t < 3; t++){
        acc_i[ta][t] = (f32x4){0.f,0.f,0.f,0.f};
        acc_h[ta][t] = (f32x4){0.f,0.f,0.f,0.f};
      }

    #pragma unroll
    for (int ks = 0; ks < 4; ks++){
      const int c = (ks*4 + aq) ^ sw;
      bf16x8 ih0 = *(const bf16x8*)(s_ah + ar*DD       + c*8);
      bf16x8 ih1 = *(const bf16x8*)(s_ah + (16+ar)*DD  + c*8);
      bf16x8 il0 = *(const bf16x8*)(s_al + ar*DD       + c*8);
      bf16x8 il1 = *(const bf16x8*)(s_al + (16+ar)*DD  + c*8);
      bf16x8 hh0 = *(const bf16x8*)(phc_hi + p0 + ks*32);
      bf16x8 hh1 = *(const bf16x8*)(phc_hi + p1 + ks*32);
      bf16x8 hl0 = *(const bf16x8*)(phc_lo + p0 + ks*32);
      bf16x8 hl1 = *(const bf16x8*)(phc_lo + p1 + ks*32);
      #pragma unroll
      for (int t = 0; t < 3; t++){
        size_t bo = ((size_t)((fg*3 + t)*4 + ks)*64 + l)*8;
        bf16x8 bih = *(const bf16x8*)(Wih_hi + bo);
        bf16x8 bil = *(const bf16x8*)(Wih_lo + bo);
        bf16x8 bhh = *(const bf16x8*)(Whh_hi + bo);
        bf16x8 bhl = *(const bf16x8*)(Whh_lo + bo);
        acc_i[0][t] = __builtin_amdgcn_mfma_f32_16x16x32_bf16(ih0, bih, acc_i[0][t], 0, 0, 0);
        acc_i[0][t] = __builtin_amdgcn_mfma_f32_16x16x32_bf16(ih0, bil, acc_i[0][t], 0, 0, 0);
        acc_i[0][t] = __builtin_amdgcn_mfma_f32_16x16x32_bf16(il0, bih, acc_i[0][t], 0, 0, 0);
        acc_i[1][t] = __builtin_amdgcn_mfma_f32_16x16x32_bf16(ih1, bih, acc_i[1][t], 0, 0, 0);
        acc_i[1][t] = __builtin_amdgcn_mfma_f32_16x16x32_bf16(ih1, bil, acc_i[1][t], 0, 0, 0);
        acc_i[1][t] = __builtin_amdgcn_mfma_f32_16x16x32_bf16(il1, bih, acc_i[1][t], 0, 0, 0);
        acc_h[0][t] = __builtin_amdgcn_mfma_f32_16x16x32_bf16(hh0, bhh, acc_h[0][t], 0, 0, 0);
        acc_h[0][t] = __builtin_amdgcn_mfma_f32_16x16x32_bf16(hh0, bhl, acc_h[0][t], 0, 0, 0);
        acc_h[0][t] = __builtin_amdgcn_mfma_f32_16x16x32_bf16(hl0, bhh, acc_h[0][t], 0, 0, 0);
        acc_h[1][t] = __builtin_amdgcn_mfma_f32_16x16x32_bf16(hh1, bhh, acc_h[1][t], 0, 0, 0);
        acc_h[1][t] = __builtin_amdgcn_mfma_f32_16x16x32_bf16(hh1, bhl, acc_h[1][t], 0, 0, 0);
        acc_h[1][t] = __builtin_amdgcn_mfma_f32_16x16x32_bf16(hl1, bhh, acc_h[1][t], 0, 0, 0);
      }
    }

    const int f = fg*16 + ar;
    const float bir = b_ih[f], biz = b_ih[128+f], bin_ = b_ih[256+f];
    const float bhr = b_hh[f], bhz = b_hh[128+f], bhn = b_hh[256+f];
    #pragma unroll
    for (int ta = 0; ta < 2; ta++){
      #pragma unroll
      for (int r = 0; r < 4; r++){
        int n = n0 + ta*16 + aq*4 + r;
        if (n < N){
          float sir = acc_i[ta][0][r] + bir, shr = acc_h[ta][0][r] + bhr;
          float siz = acc_i[ta][1][r] + biz, shz = acc_h[ta][1][r] + bhz;
          float sin_ = acc_i[ta][2][r] + bin_, shn = acc_h[ta][2][r] + bhn;
          float rr = sigmoidf_(sir + shr);
          float zz = sigmoidf_(siz + shz);
          float nn = tanhf_(sin_ + rr*shn);
          size_t o = (size_t)n*DD + f;
          float hp = b2f(phc_hi[o]) + b2f(phc_lo[o]);
          float h = (1.f - zz)*nn + zz*hp;
          unsigned short hi, lo; bsplit(h, hi, lo);
          phn_hi[o] = hi; phn_lo[o] = lo;
        }
      }
    }
  }
}

// ---------- decoder stage 1: 8 split stats copies to cap atomic contention ----------
__global__ void __launch_bounds__(256) k_dec1(const float* __restrict__ h_sum,
        const float* __restrict__ Wt_dec, float* __restrict__ y1,
        float* __restrict__ stats_d, int N){
  const int j = threadIdx.x & 63;
  const int slot = threadIdx.x >> 6;
  float s = 0.f, q = 0.f;
  for (int n = blockIdx.x*4 + slot; n < N; n += gridDim.x*4){
    float acc = 0.f;
    for (int k = 0; k < DD; k += 4){
      float4 zv = *(const float4*)(h_sum + (size_t)n*DD + k);
      float4 wv = *(const float4*)(Wt_dec + ((size_t)(k>>2)*64 + j)*4);
      acc += zv.x*wv.x + zv.y*wv.y + zv.z*wv.z + zv.w*wv.w;
    }
    acc *= (1.f/6.f);
    y1[(size_t)n*64 + j] = acc;
    s += acc; q += acc*acc;
  }
  __shared__ float red[2][4][64];
  red[0][slot][j] = s; red[1][slot][j] = q;
  __syncthreads();
  if (slot == 0){
    s = red[0][0][j] + red[0][1][j] + red[0][2][j] + red[0][3][j];
    q = red[1][0][j] + red[1][1][j] + red[1][2][j] + red[1][3][j];
    float* st = stats_d + (size_t)(blockIdx.x & 7)*128;
    atomicAdd(&st[j], s);
    atomicAdd(&st[64+j], q);
  }
}

// ---------- decoder stage 2: sum stats copies, bn + relu + dot ----------
__global__ void __launch_bounds__(256) k_dec2(const float* __restrict__ y1,
        const float* __restrict__ gamma, const float* __restrict__ beta,
        const float* __restrict__ W_dec2, const float* __restrict__ stats_d,
        float* __restrict__ out, int N){
  const int j = threadIdx.x & 63;
  const int g = threadIdx.x >> 6;
  const int n = blockIdx.x*4 + g;
  if (n >= N) return;
  float ssum = 0.f, qsum = 0.f;
  #pragma unroll
  for (int c = 0; c < 8; c++){
    ssum += stats_d[c*128 + j];
    qsum += stats_d[c*128 + 64 + j];
  }
  float invN = 1.f / (float)N;
  float mu = ssum * invN;
  float var = qsum * invN - mu*mu;
  float v = (y1[(size_t)n*64 + j] - mu) * rsqrtf(var + 1e-5f) * gamma[j] + beta[j];
  v = fmaxf(v, 0.f) * W_dec2[j];
  for (int off = 32; off > 0; off >>= 1) v += __shfl_down(v, off, 64);
  if (j == 0) out[n] = v;
}

extern "C" void kernel_launch(void* const* d_in, const int* in_sizes, int n_in,
                              void* d_out, int out_size, void* d_ws, size_t ws_size,
                              hipStream_t stream) {
  const int N = in_sizes[0] / 3;
  const int E = in_sizes[1] / 2;
  const int P = (N + 255) / 256;

  const float* x     = (const float*)d_in[0];
  const int*   ei    = (const int*)d_in[1];
  const int*   src   = ei;
  const int*   dst   = ei + E;
  const float* norm  = (const float*)d_in[2];
  const float* W_enc = (const float*)d_in[3];
  const float* g_e   = (const float*)d_in[4];
  const float* b_e   = (const float*)d_in[5];
  const float* W_ih  = (const float*)d_in[6];
  const float* W_hh  = (const float*)d_in[7];
  const float* b_ih  = (const float*)d_in[8];
  const float* b_hh  = (const float*)d_in[9];
  const float* W_dec = (const float*)d_in[10];
  const float* g_d   = (const float*)d_in[11];
  const float* b_d   = (const float*)d_in[12];
  const float* W_dec2= (const float*)d_in[13];
  float* out = (float*)d_out;

  float* ws = (float*)d_ws;
  const size_t NF = (size_t)N * DD;
  float* scr    = ws;                        // NF fp32: h0 (pre-loop) / y1 (post-loop)
  float* h_sum  = scr + NF;                  // NF
  float* stats  = h_sum + NF;                // 256 enc + 1024 dec
  float* Wt_dec = stats + 1280;              // 64*128
  unsigned short* Wih_hi = (unsigned short*)(Wt_dec + 64*128);
  unsigned short* Wih_lo = Wih_hi + 384*128;
  unsigned short* Whh_hi = Wih_lo + 384*128;
  unsigned short* Whh_lo = Whh_hi + 384*128;
  unsigned short* ph_hiA = Whh_lo + 384*128; // NF ushorts each
  unsigned short* ph_loA = ph_hiA + NF;
  unsigned short* ph_hiB = ph_loA + NF;
  unsigned short* ph_loB = ph_hiB + NF;
  int*   counts  = (int*)(ph_loB + NF);      // N
  int*   offsets = counts + N;               // N+1
  int*   cursors = offsets + N + 1;          // N
  int*   partials= cursors + N;              // P
  int*   csr_src = partials + P;             // E
  float* csr_norm = (float*)(csr_src + E);   // E
  float* h0 = scr;
  float* y1 = scr;

  hipMemsetAsync(stats, 0, 1280*sizeof(float), stream);
  hipMemsetAsync(counts, 0, (size_t)N*sizeof(int), stream);

  k_prep<<<(64*128 + 255)/256, 256, 0, stream>>>(W_dec, Wt_dec);
  k_prep_frag<<<(2*384*128 + 255)/256, 256, 0, stream>>>(W_ih, W_hh, Wih_hi, Wih_lo, Whh_hi, Whh_lo);
  k_enc<<<256, 128, 0, stream>>>(x, W_enc, h0, stats, N);
  k_enc_apply<<<(N*DD + 255)/256, 256, 0, stream>>>(h0, g_e, b_e, stats, h_sum, ph_hiA, ph_loA, N);

  k_hist<<<(E + 255)/256, 256, 0, stream>>>(dst, counts, E);
  k_scan_part<<<P, 256, 0, stream>>>(counts, partials, N);
  k_scan_mid<<<1, 256, 0, stream>>>(partials, P, offsets, N);
  k_scan_expand<<<P, 256, 0, stream>>>(counts, partials, offsets, cursors, N);
  k_fill<<<(E + 255)/256, 256, 0, stream>>>(src, dst, norm, cursors, csr_src, csr_norm, E);

  unsigned short* phh_c = ph_hiA; unsigned short* phl_c = ph_loA;
  unsigned short* phh_n = ph_hiB; unsigned short* phl_n = ph_loB;
  for (int l = 0; l < 5; l++){
    k_layer<<<(N + 31)/32, 256, 0, stream>>>(phh_c, phl_c, phh_n, phl_n, h_sum,
                                             offsets, csr_src, csr_norm,
                                             Wih_hi, Wih_lo, Whh_hi, Whh_lo, b_ih, b_hh, N);
    { unsigned short* t = phh_c; phh_c = phh_n; phh_n = t; }
    { unsigned short* t = phl_c; phl_c = phl_n; phl_n = t; }
  }

  k_dec1<<<1024, 256, 0, stream>>>(h_sum, Wt_dec, y1, stats + 256, N);
  k_dec2<<<(N + 3)/4, 256, 0, stream>>>(y1, g_d, b_d, W_dec2, stats + 256, out, N);
}